// Round 1
// baseline (1203.768 us; speedup 1.0000x reference)
//
#include <hip/hip_runtime.h>
#include <cstdint>
#include <cstddef>

#define NN 50000
#define EE 640000
#define DD 128
#define LL 3
#define GG 256
#define LATD 64

// ---------- CSR build ----------
__global__ __launch_bounds__(256) void hist_kernel(const int* __restrict__ dst,
                                                   int* __restrict__ counts, int E) {
  int e = blockIdx.x * blockDim.x + threadIdx.x;
  if (e < E) atomicAdd(&counts[dst[e]], 1);
}

__global__ __launch_bounds__(1024) void scan_kernel(const int* __restrict__ counts,
                                                    int* __restrict__ row_ptr,
                                                    int* __restrict__ cursor, int n) {
  __shared__ int buf[1024];
  __shared__ int carry;
  if (threadIdx.x == 0) carry = 0;
  __syncthreads();
  for (int base = 0; base < n; base += 1024) {
    int i = base + (int)threadIdx.x;
    int v = (i < n) ? counts[i] : 0;
    buf[threadIdx.x] = v;
    __syncthreads();
    for (int off = 1; off < 1024; off <<= 1) {
      int t = (threadIdx.x >= (unsigned)off) ? buf[threadIdx.x - off] : 0;
      __syncthreads();
      buf[threadIdx.x] += t;
      __syncthreads();
    }
    int incl = buf[threadIdx.x];
    int excl = incl - v;
    int c = carry;
    if (i < n) { row_ptr[i] = c + excl; cursor[i] = c + excl; }
    __syncthreads();
    if (threadIdx.x == 1023) carry = c + incl;
    __syncthreads();
  }
  if (threadIdx.x == 0) row_ptr[n] = carry;
}

__global__ __launch_bounds__(256) void fill_kernel(const int* __restrict__ src,
                                                   const int* __restrict__ dst,
                                                   int* __restrict__ cursor,
                                                   int* __restrict__ col, int E) {
  int e = blockIdx.x * blockDim.x + threadIdx.x;
  if (e < E) {
    int p = atomicAdd(&cursor[dst[e]], 1);
    col[p] = src[e];
  }
}

// ---------- GIN aggregation: agg[n] = x[n] + sum_{j in N_in(n)} x[j] ----------
__global__ __launch_bounds__(256) void agg_kernel(const float4* __restrict__ xin,
                                                  const int* __restrict__ row_ptr,
                                                  const int* __restrict__ col,
                                                  float4* __restrict__ agg, int n) {
  int tid = blockIdx.x * blockDim.x + threadIdx.x;
  int node = tid >> 5;
  int c = tid & 31;
  if (node >= n) return;
  float4 acc = xin[(size_t)node * 32 + c];
  int s = row_ptr[node], e = row_ptr[node + 1];
  for (int j = s; j < e; ++j) {
    int sc = col[j];
    float4 v = xin[(size_t)sc * 32 + c];
    acc.x += v.x; acc.y += v.y; acc.z += v.z; acc.w += v.w;
  }
  agg[(size_t)node * 32 + c] = acc;
}

// ---------- fused MLP: x = leaky(bn(leaky(agg@W1^T+b1))@W2^T + b2) ----------
__global__ __launch_bounds__(512) void mlp_kernel(const float* __restrict__ agg,
    float* __restrict__ xout,
    const float* __restrict__ W1, const float* __restrict__ b1,
    const float* __restrict__ bng, const float* __restrict__ bnb,
    const float* __restrict__ bnm, const float* __restrict__ bnv,
    const float* __restrict__ W2, const float* __restrict__ b2,
    int n, int total_waves) {
  __shared__ float w1t[DD * DD];
  __shared__ float w2t[DD * DD];
  for (int idx = threadIdx.x; idx < DD * DD; idx += blockDim.x) {
    int o = idx >> 7, k = idx & 127;
    w1t[k * DD + o] = W1[idx];   // w1t[k][d] = W1[d][k]
    w2t[k * DD + o] = W2[idx];
  }
  __syncthreads();
  int lane = threadIdx.x & 63;
  int l2 = lane + 64;
  float b1a = b1[lane], b1b = b1[l2];
  float sa = bng[lane] * rsqrtf(bnv[lane] + 1e-5f);
  float sb = bng[l2]   * rsqrtf(bnv[l2]   + 1e-5f);
  float ta = bnb[lane] - bnm[lane] * sa;
  float tb = bnb[l2]   - bnm[l2]   * sb;
  float b2a = b2[lane], b2b = b2[l2];

  int gwave = blockIdx.x * (blockDim.x >> 6) + (threadIdx.x >> 6);
  for (int row = gwave; row < n; row += total_waves) {
    float2 v = ((const float2*)(agg + (size_t)row * DD))[lane];
    float acc0 = 0.f, acc1 = 0.f, acc2 = 0.f, acc3 = 0.f;
#pragma unroll 8
    for (int k = 0; k < DD; k += 2) {
      float a0 = __shfl(v.x, k >> 1);
      float a1 = __shfl(v.y, k >> 1);
      acc0 = fmaf(a0, w1t[k * DD + lane], acc0);
      acc1 = fmaf(a0, w1t[k * DD + l2], acc1);
      acc2 = fmaf(a1, w1t[(k + 1) * DD + lane], acc2);
      acc3 = fmaf(a1, w1t[(k + 1) * DD + l2], acc3);
    }
    float h0 = acc0 + acc2 + b1a;
    float h1 = acc1 + acc3 + b1b;
    h0 = h0 >= 0.f ? h0 : 0.2f * h0;
    h1 = h1 >= 0.f ? h1 : 0.2f * h1;
    h0 = h0 * sa + ta;
    h1 = h1 * sb + tb;
    float o0 = 0.f, o1 = 0.f, o2 = 0.f, o3 = 0.f;
#pragma unroll 8
    for (int k = 0; k < 64; k += 2) {
      float a0 = __shfl(h0, k);
      float a1 = __shfl(h0, k + 1);
      float c0 = __shfl(h1, k);
      float c1 = __shfl(h1, k + 1);
      o0 = fmaf(a0, w2t[k * DD + lane], o0);
      o1 = fmaf(a0, w2t[k * DD + l2], o1);
      o2 = fmaf(a1, w2t[(k + 1) * DD + lane], o2);
      o3 = fmaf(a1, w2t[(k + 1) * DD + l2], o3);
      o0 = fmaf(c0, w2t[(k + 64) * DD + lane], o0);
      o1 = fmaf(c0, w2t[(k + 64) * DD + l2], o1);
      o2 = fmaf(c1, w2t[(k + 65) * DD + lane], o2);
      o3 = fmaf(c1, w2t[(k + 65) * DD + l2], o3);
    }
    float x0 = o0 + o2 + b2a;
    float x1 = o1 + o3 + b2b;
    x0 = x0 >= 0.f ? x0 : 0.2f * x0;
    x1 = x1 >= 0.f ? x1 : 0.2f * x1;
    xout[(size_t)row * DD + lane] = x0;
    xout[(size_t)row * DD + l2]   = x1;
  }
}

// ---------- pooling: pooled[g] += x[n] for batch[n]==g ----------
__global__ __launch_bounds__(256) void pool_kernel(const float* __restrict__ x,
    const int* __restrict__ batch, float* __restrict__ pooled, int n) {
  int tid = blockIdx.x * blockDim.x + threadIdx.x;
  int node = tid >> 5;
  int c = tid & 31;
  if (node >= n) return;
  const float4 v = ((const float4*)x)[(size_t)node * 32 + c];
  int g = batch[node];
  float* p = pooled + (size_t)g * DD + c * 4;
  atomicAdd(p + 0, v.x); atomicAdd(p + 1, v.y);
  atomicAdd(p + 2, v.z); atomicAdd(p + 3, v.w);
}

// ---------- head: out = bn(pooled) @ fcW^T + fcb ----------
__global__ __launch_bounds__(256) void final_kernel(const float* __restrict__ pooled,
    const float* __restrict__ og, const float* __restrict__ ob,
    const float* __restrict__ om, const float* __restrict__ ov,
    const float* __restrict__ fcW, const float* __restrict__ fcb,
    float* __restrict__ out) {
  int tid = blockIdx.x * blockDim.x + threadIdx.x;
  if (tid >= GG * LATD) return;
  int g = tid >> 6, l = tid & 63;
  float acc = fcb[l];
  for (int d = 0; d < DD; ++d) {
    float s = og[d] * rsqrtf(ov[d] + 1e-5f);
    float pb = (pooled[(size_t)g * DD + d] - om[d]) * s + ob[d];
    acc = fmaf(fcW[l * DD + d], pb, acc);
  }
  out[tid] = acc;
}

extern "C" void kernel_launch(void* const* d_in, const int* in_sizes, int n_in,
                              void* d_out, int out_size, void* d_ws, size_t ws_size,
                              hipStream_t stream) {
  const float* x   = (const float*)d_in[0];
  const float* W1  = (const float*)d_in[1];
  const float* b1  = (const float*)d_in[2];
  const float* bng = (const float*)d_in[3];
  const float* bnb = (const float*)d_in[4];
  const float* bnm = (const float*)d_in[5];
  const float* bnv = (const float*)d_in[6];
  const float* W2  = (const float*)d_in[7];
  const float* b2  = (const float*)d_in[8];
  const float* og  = (const float*)d_in[9];
  const float* ob  = (const float*)d_in[10];
  const float* om  = (const float*)d_in[11];
  const float* ov  = (const float*)d_in[12];
  const float* fcW = (const float*)d_in[13];
  const float* fcb = (const float*)d_in[14];
  const int* ei    = (const int*)d_in[15];
  const int* batch = (const int*)d_in[16];
  const int* src  = ei;
  const int* dstp = ei + EE;

  char* ws = (char*)d_ws;
  size_t off = 0;
  auto alloc = [&](size_t bytes) {
    void* p = ws + off;
    off += (bytes + 255) & ~(size_t)255;
    return p;
  };
  float* xbuf    = (float*)alloc((size_t)NN * DD * 4);
  float* aggb    = (float*)alloc((size_t)NN * DD * 4);
  int* row_ptr   = (int*)alloc((NN + 1) * 4);
  int* cursor    = (int*)alloc(NN * 4);
  int* counts    = (int*)alloc(NN * 4);
  int* col       = (int*)alloc(EE * 4);
  float* pooled  = (float*)alloc(GG * DD * 4);

  hipMemsetAsync(counts, 0, NN * 4, stream);
  hist_kernel<<<(EE + 255) / 256, 256, 0, stream>>>(dstp, counts, EE);
  scan_kernel<<<1, 1024, 0, stream>>>(counts, row_ptr, cursor, NN);
  fill_kernel<<<(EE + 255) / 256, 256, 0, stream>>>(src, dstp, cursor, col, EE);

  hipMemsetAsync(pooled, 0, GG * DD * 4, stream);

  const float* xcur = x;
  for (int i = 0; i < LL; ++i) {
    agg_kernel<<<(NN * 32 + 255) / 256, 256, 0, stream>>>(
        (const float4*)xcur, row_ptr, col, (float4*)aggb, NN);
    mlp_kernel<<<256, 512, 0, stream>>>(
        aggb, xbuf,
        W1 + (size_t)i * DD * DD, b1 + i * DD,
        bng + i * DD, bnb + i * DD, bnm + i * DD, bnv + i * DD,
        W2 + (size_t)i * DD * DD, b2 + i * DD,
        NN, 256 * 8);
    xcur = xbuf;
  }
  pool_kernel<<<(NN * 32 + 255) / 256, 256, 0, stream>>>(xcur, batch, pooled, NN);
  final_kernel<<<(GG * LATD + 255) / 256, 256, 0, stream>>>(
      pooled, og, ob, om, ov, fcW, fcb, (float*)d_out);
}

// Round 2
// 264.512 us; speedup vs baseline: 4.5509x; 4.5509x over previous
//
#include <hip/hip_runtime.h>
#include <cstdint>
#include <cstddef>

#define NN 50000
#define EE 640000
#define DD 128
#define LL 3
#define GG 256
#define LATD 64

typedef __attribute__((ext_vector_type(8))) __bf16 bf16x8;
typedef __attribute__((ext_vector_type(4))) float f32x4;

__device__ __forceinline__ unsigned short f2bf(float f) {
  __bf16 h = (__bf16)f;
  return __builtin_bit_cast(unsigned short, h);
}
__device__ __forceinline__ float bf2f(unsigned int u16) {
  unsigned int x = u16 << 16;
  return __builtin_bit_cast(float, x);
}
__device__ __forceinline__ void unpack8(uint4 v, float* f) {
  f[0] = bf2f(v.x & 0xffffu); f[1] = bf2f(v.x >> 16);
  f[2] = bf2f(v.y & 0xffffu); f[3] = bf2f(v.y >> 16);
  f[4] = bf2f(v.z & 0xffffu); f[5] = bf2f(v.z >> 16);
  f[6] = bf2f(v.w & 0xffffu); f[7] = bf2f(v.w >> 16);
}

// ---------- x fp32 -> bf16 ----------
__global__ __launch_bounds__(256) void cvt_kernel(const float4* __restrict__ x,
                                                  uint4* __restrict__ xb, int n8) {
  int t = blockIdx.x * 256 + threadIdx.x;
  if (t >= n8) return;
  float4 a = x[t * 2], b = x[t * 2 + 1];
  uint4 v;
  v.x = f2bf(a.x) | ((unsigned)f2bf(a.y) << 16);
  v.y = f2bf(a.z) | ((unsigned)f2bf(a.w) << 16);
  v.z = f2bf(b.x) | ((unsigned)f2bf(b.y) << 16);
  v.w = f2bf(b.z) | ((unsigned)f2bf(b.w) << 16);
  xb[t] = v;
}

// ---------- CSR build ----------
__global__ __launch_bounds__(256) void hist_kernel(const int* __restrict__ dst,
                                                   int* __restrict__ counts, int E) {
  int e = blockIdx.x * blockDim.x + threadIdx.x;
  if (e < E) atomicAdd(&counts[dst[e]], 1);
}

__global__ __launch_bounds__(256) void scan1_kernel(const int* __restrict__ counts,
                                                    int* __restrict__ rp,
                                                    int* __restrict__ bsum, int n) {
  int i = blockIdx.x * 256 + threadIdx.x;
  int v = (i < n) ? counts[i] : 0;
  int lane = threadIdx.x & 63, w = threadIdx.x >> 6;
  int s = v;
#pragma unroll
  for (int off = 1; off < 64; off <<= 1) {
    int u = __shfl_up(s, off);
    if (lane >= off) s += u;
  }
  __shared__ int ws[4];
  if (lane == 63) ws[w] = s;
  __syncthreads();
  int add = 0;
#pragma unroll
  for (int k = 0; k < 4; ++k) if (k < w) add += ws[k];
  int incl = s + add;
  if (i < n) rp[i] = incl - v;              // block-local exclusive
  if (threadIdx.x == 255) bsum[blockIdx.x] = incl;
}

__global__ __launch_bounds__(256) void scan2_kernel(int* __restrict__ bsum, int nb) {
  int t = threadIdx.x;
  int v = (t < nb) ? bsum[t] : 0;
  int lane = t & 63, w = t >> 6;
  int s = v;
#pragma unroll
  for (int off = 1; off < 64; off <<= 1) {
    int u = __shfl_up(s, off);
    if (lane >= off) s += u;
  }
  __shared__ int ws[4];
  if (lane == 63) ws[w] = s;
  __syncthreads();
  int add = 0;
#pragma unroll
  for (int k = 0; k < 4; ++k) if (k < w) add += ws[k];
  int incl = s + add;
  if (t < nb) bsum[t] = incl - v;           // exclusive
}

__global__ __launch_bounds__(256) void scan3_kernel(int* __restrict__ rp,
                                                    int* __restrict__ cursor,
                                                    const int* __restrict__ bsum, int n) {
  int i = blockIdx.x * 256 + threadIdx.x;
  if (i < n) {
    int v = rp[i] + bsum[blockIdx.x];
    rp[i] = v;
    cursor[i] = v;
  }
  if (i == 0) rp[n] = EE;
}

__global__ __launch_bounds__(256) void fill_kernel(const int* __restrict__ src,
                                                   const int* __restrict__ dst,
                                                   int* __restrict__ cursor,
                                                   int* __restrict__ col, int E) {
  int e = blockIdx.x * blockDim.x + threadIdx.x;
  if (e < E) {
    int p = atomicAdd(&cursor[dst[e]], 1);
    col[p] = src[e];
  }
}

// ---------- GIN aggregation (bf16 in, bf16 out, fp32 accum) ----------
__global__ __launch_bounds__(256) void agg_kernel(const uint4* __restrict__ xin,
                                                  const int* __restrict__ row_ptr,
                                                  const int* __restrict__ col,
                                                  uint4* __restrict__ agg, int n) {
  int tid = blockIdx.x * 256 + threadIdx.x;
  int node = tid >> 4;
  int c = tid & 15;
  if (node >= n) return;
  float acc[8], tmp[8];
  unpack8(xin[(size_t)node * 16 + c], acc);
  int s = row_ptr[node], e = row_ptr[node + 1];
  for (int j = s; j < e; ++j) {
    int sc = col[j];
    unpack8(xin[(size_t)sc * 16 + c], tmp);
#pragma unroll
    for (int i = 0; i < 8; ++i) acc[i] += tmp[i];
  }
  uint4 v;
  v.x = f2bf(acc[0]) | ((unsigned)f2bf(acc[1]) << 16);
  v.y = f2bf(acc[2]) | ((unsigned)f2bf(acc[3]) << 16);
  v.z = f2bf(acc[4]) | ((unsigned)f2bf(acc[5]) << 16);
  v.w = f2bf(acc[6]) | ((unsigned)f2bf(acc[7]) << 16);
  agg[(size_t)node * 16 + c] = v;
}

// ---------- fused MFMA MLP ----------
// h = leaky(agg@W1^T+b1); h = h*s+t (BN); x = leaky(h@W2^T+b2)
// LDS: W1 [128][128] bf16 (32KB) + W2 (32KB) + X [256][128] bf16 (64KB), all
// XOR-swizzled: byte ^= (row&7)<<4 (rows are 256B apart -> unswizzled ds_read_b128
// would be 32-way bank conflict, §6 G4).
#define SWZ(byte_, row_) ((byte_) ^ (((row_) & 7) << 4))

__global__ __launch_bounds__(512, 2) void mlp_mfma(
    const unsigned short* __restrict__ agg, unsigned short* __restrict__ xout,
    const float* __restrict__ W1, const float* __restrict__ b1,
    const float* __restrict__ bng, const float* __restrict__ bnb,
    const float* __restrict__ bnm, const float* __restrict__ bnv,
    const float* __restrict__ W2, const float* __restrict__ b2, int n) {
  __shared__ __align__(16) char smem[131072];
  char* w1p = smem;
  char* w2p = smem + 32768;
  char* xp  = smem + 65536;

  // stage weights fp32->bf16 (both matrices, row-major [out][in] == B operand rows)
#pragma unroll
  for (int it = 0; it < 8; ++it) {
    int chunk = it * 512 + threadIdx.x;      // 4096 chunks of 4 floats
    int row = chunk >> 5, k4 = chunk & 31;
    int byte = SWZ(row * 256 + k4 * 8, row);
    float4 f = ((const float4*)W1)[chunk];
    *(uint2*)(w1p + byte) = make_uint2(
        f2bf(f.x) | ((unsigned)f2bf(f.y) << 16),
        f2bf(f.z) | ((unsigned)f2bf(f.w) << 16));
    float4 g = ((const float4*)W2)[chunk];
    *(uint2*)(w2p + byte) = make_uint2(
        f2bf(g.x) | ((unsigned)f2bf(g.y) << 16),
        f2bf(g.z) | ((unsigned)f2bf(g.w) << 16));
  }
  // stage X tile (bf16, already packed in global)
  int base = blockIdx.x * 256;
#pragma unroll
  for (int it = 0; it < 8; ++it) {
    int chunk = it * 512 + threadIdx.x;      // 4096 chunks of 16B
    int row = chunk >> 4, kc = chunk & 15;
    int grow = base + row;
    uint4 v = make_uint4(0, 0, 0, 0);
    if (grow < n) v = ((const uint4*)agg)[(size_t)grow * 16 + kc];
    *(uint4*)(xp + SWZ(row * 256 + kc * 16, row)) = v;
  }
  __syncthreads();

  int lane = threadIdx.x & 63;
  int c = lane & 15;
  int half = lane >> 4;
  int wave = threadIdx.x >> 6;
  int Rw = wave * 32;

  float b1v[8], sv[8], tv[8], b2v[8];
#pragma unroll
  for (int ni = 0; ni < 8; ++ni) {
    int cc = ni * 16 + c;
    b1v[ni] = b1[cc];
    float s = bng[cc] * rsqrtf(bnv[cc] + 1e-5f);
    sv[ni] = s;
    tv[ni] = bnb[cc] - bnm[cc] * s;
    b2v[ni] = b2[cc];
  }

  f32x4 acc[2][8];
#pragma unroll
  for (int mi = 0; mi < 2; ++mi)
#pragma unroll
    for (int ni = 0; ni < 8; ++ni) acc[mi][ni] = (f32x4){0.f, 0.f, 0.f, 0.f};

  // GEMM1: h = X @ W1^T
#pragma unroll
  for (int ks = 0; ks < 4; ++ks) {
    bf16x8 a[2];
#pragma unroll
    for (int mi = 0; mi < 2; ++mi) {
      int row = Rw + mi * 16 + c;
      a[mi] = *(const bf16x8*)(xp + SWZ(row * 256 + ks * 64 + half * 16, row));
    }
#pragma unroll
    for (int ni = 0; ni < 8; ++ni) {
      int wr = ni * 16 + c;
      bf16x8 bf = *(const bf16x8*)(w1p + SWZ(wr * 256 + ks * 64 + half * 16, wr));
      acc[0][ni] = __builtin_amdgcn_mfma_f32_16x16x32_bf16(a[0], bf, acc[0][ni], 0, 0, 0);
      acc[1][ni] = __builtin_amdgcn_mfma_f32_16x16x32_bf16(a[1], bf, acc[1][ni], 0, 0, 0);
    }
  }

  // epilogue 1: leaky + BN, write h back to X (bf16, swizzled). Each wave touches
  // only its own 32 rows, so no cross-wave hazard; barrier kept for safety.
#pragma unroll
  for (int mi = 0; mi < 2; ++mi)
#pragma unroll
    for (int ni = 0; ni < 8; ++ni)
#pragma unroll
      for (int r = 0; r < 4; ++r) {
        float h = acc[mi][ni][r] + b1v[ni];
        h = h >= 0.f ? h : 0.2f * h;
        h = h * sv[ni] + tv[ni];
        int row = Rw + mi * 16 + half * 4 + r;
        int colb = (ni * 16 + c) * 2;
        *(__bf16*)(xp + SWZ(row * 256 + colb, row)) = (__bf16)h;
      }
  __syncthreads();

#pragma unroll
  for (int mi = 0; mi < 2; ++mi)
#pragma unroll
    for (int ni = 0; ni < 8; ++ni) acc[mi][ni] = (f32x4){0.f, 0.f, 0.f, 0.f};

  // GEMM2: x = h @ W2^T
#pragma unroll
  for (int ks = 0; ks < 4; ++ks) {
    bf16x8 a[2];
#pragma unroll
    for (int mi = 0; mi < 2; ++mi) {
      int row = Rw + mi * 16 + c;
      a[mi] = *(const bf16x8*)(xp + SWZ(row * 256 + ks * 64 + half * 16, row));
    }
#pragma unroll
    for (int ni = 0; ni < 8; ++ni) {
      int wr = ni * 16 + c;
      bf16x8 bf = *(const bf16x8*)(w2p + SWZ(wr * 256 + ks * 64 + half * 16, wr));
      acc[0][ni] = __builtin_amdgcn_mfma_f32_16x16x32_bf16(a[0], bf, acc[0][ni], 0, 0, 0);
      acc[1][ni] = __builtin_amdgcn_mfma_f32_16x16x32_bf16(a[1], bf, acc[1][ni], 0, 0, 0);
    }
  }

  // epilogue 2: leaky, store bf16 to global
#pragma unroll
  for (int mi = 0; mi < 2; ++mi)
#pragma unroll
    for (int ni = 0; ni < 8; ++ni)
#pragma unroll
      for (int r = 0; r < 4; ++r) {
        float xo = acc[mi][ni][r] + b2v[ni];
        xo = xo >= 0.f ? xo : 0.2f * xo;
        int grow = base + Rw + mi * 16 + half * 4 + r;
        if (grow < n) xout[(size_t)grow * DD + ni * 16 + c] = f2bf(xo);
      }
}

// ---------- pooling: batch is sorted -> run-accumulate, flush on graph change ----------
__global__ __launch_bounds__(256) void pool_kernel(const uint4* __restrict__ x,
                                                   const int* __restrict__ batch,
                                                   float* __restrict__ pooled, int n) {
  int gid = blockIdx.x * 256 + threadIdx.x;
  int grp = gid >> 4, c = gid & 15;
  int n0 = grp * 16;
  if (n0 >= n) return;
  float acc[8] = {0.f, 0.f, 0.f, 0.f, 0.f, 0.f, 0.f, 0.f};
  int curg = batch[n0];
  int end = n0 + 16 < n ? n0 + 16 : n;
  for (int node = n0; node < end; ++node) {
    int g = batch[node];
    if (g != curg) {
      float* p = pooled + (size_t)curg * DD + c * 8;
#pragma unroll
      for (int i = 0; i < 8; ++i) { atomicAdd(p + i, acc[i]); acc[i] = 0.f; }
      curg = g;
    }
    float tmp[8];
    unpack8(x[(size_t)node * 16 + c], tmp);
#pragma unroll
    for (int i = 0; i < 8; ++i) acc[i] += tmp[i];
  }
  float* p = pooled + (size_t)curg * DD + c * 8;
#pragma unroll
  for (int i = 0; i < 8; ++i) atomicAdd(p + i, acc[i]);
}

// ---------- head: out[g] = bn(pooled[g]) @ fcW^T + fcb ----------
__global__ __launch_bounds__(128) void head_kernel(const float* __restrict__ pooled,
    const float* __restrict__ og, const float* __restrict__ ob,
    const float* __restrict__ om, const float* __restrict__ ov,
    const float* __restrict__ fcW, const float* __restrict__ fcb,
    float* __restrict__ out) {
  __shared__ float pb[DD];
  int g = blockIdx.x;
  int t = threadIdx.x;
  float s = og[t] * rsqrtf(ov[t] + 1e-5f);
  pb[t] = (pooled[(size_t)g * DD + t] - om[t]) * s + ob[t];
  __syncthreads();
  if (t < LATD) {
    float acc = fcb[t];
#pragma unroll 8
    for (int d = 0; d < DD; ++d) acc = fmaf(fcW[t * DD + d], pb[d], acc);
    out[(size_t)g * LATD + t] = acc;
  }
}

extern "C" void kernel_launch(void* const* d_in, const int* in_sizes, int n_in,
                              void* d_out, int out_size, void* d_ws, size_t ws_size,
                              hipStream_t stream) {
  const float* x   = (const float*)d_in[0];
  const float* W1  = (const float*)d_in[1];
  const float* b1  = (const float*)d_in[2];
  const float* bng = (const float*)d_in[3];
  const float* bnb = (const float*)d_in[4];
  const float* bnm = (const float*)d_in[5];
  const float* bnv = (const float*)d_in[6];
  const float* W2  = (const float*)d_in[7];
  const float* b2  = (const float*)d_in[8];
  const float* og  = (const float*)d_in[9];
  const float* ob  = (const float*)d_in[10];
  const float* om  = (const float*)d_in[11];
  const float* ov  = (const float*)d_in[12];
  const float* fcW = (const float*)d_in[13];
  const float* fcb = (const float*)d_in[14];
  const int* ei    = (const int*)d_in[15];
  const int* batch = (const int*)d_in[16];
  const int* src  = ei;
  const int* dstp = ei + EE;

  char* ws = (char*)d_ws;
  size_t off = 0;
  auto alloc = [&](size_t bytes) {
    void* p = ws + off;
    off += (bytes + 255) & ~(size_t)255;
    return p;
  };
  unsigned short* xb0  = (unsigned short*)alloc((size_t)NN * DD * 2);
  unsigned short* xb1  = (unsigned short*)alloc((size_t)NN * DD * 2);
  unsigned short* aggb = (unsigned short*)alloc((size_t)NN * DD * 2);
  int* row_ptr  = (int*)alloc((NN + 1) * 4);
  int* cursor   = (int*)alloc(NN * 4);
  int* counts   = (int*)alloc(NN * 4);
  int* col      = (int*)alloc(EE * 4);
  int* bsum     = (int*)alloc(256 * 4);
  float* pooled = (float*)alloc(GG * DD * 4);

  hipMemsetAsync(counts, 0, NN * 4, stream);
  hipMemsetAsync(pooled, 0, GG * DD * 4, stream);

  cvt_kernel<<<(NN * DD / 8 + 255) / 256, 256, 0, stream>>>(
      (const float4*)x, (uint4*)xb0, NN * DD / 8);

  const int NB = (NN + 255) / 256;  // 196
  hist_kernel<<<(EE + 255) / 256, 256, 0, stream>>>(dstp, counts, EE);
  scan1_kernel<<<NB, 256, 0, stream>>>(counts, row_ptr, bsum, NN);
  scan2_kernel<<<1, 256, 0, stream>>>(bsum, NB);
  scan3_kernel<<<NB, 256, 0, stream>>>(row_ptr, cursor, bsum, NN);
  fill_kernel<<<(EE + 255) / 256, 256, 0, stream>>>(src, dstp, cursor, col, EE);

  unsigned short* xcur = xb0;
  unsigned short* xnext = xb1;
  for (int i = 0; i < LL; ++i) {
    agg_kernel<<<(NN * 16 + 255) / 256, 256, 0, stream>>>(
        (const uint4*)xcur, row_ptr, col, (uint4*)aggb, NN);
    mlp_mfma<<<NB, 512, 0, stream>>>(
        aggb, xnext,
        W1 + (size_t)i * DD * DD, b1 + i * DD,
        bng + i * DD, bnb + i * DD, bnm + i * DD, bnv + i * DD,
        W2 + (size_t)i * DD * DD, b2 + i * DD, NN);
    unsigned short* t = xcur; xcur = xnext; xnext = t;
  }
  pool_kernel<<<(NN * 16 + 255) / 256, 256, 0, stream>>>(
      (const uint4*)xcur, batch, pooled, NN);
  head_kernel<<<GG, 128, 0, stream>>>(pooled, og, ob, om, ov, fcW, fcb, (float*)d_out);
}